// Round 4
// baseline (411.504 us; speedup 1.0000x reference)
//
#include <hip/hip_runtime.h>
#include <hip/hip_bf16.h>
#include <math.h>

#define B_  8
#define N_  1024
#define DM  512
#define H_  8
#define DK_ 64
#define ST  128

typedef __attribute__((ext_vector_type(8))) short short8;
typedef __attribute__((ext_vector_type(4))) float floatx4;

#define GLD16(gp, lp)                                                          \
    __builtin_amdgcn_global_load_lds(                                          \
        (const __attribute__((address_space(1))) void*)(gp),                   \
        (__attribute__((address_space(3))) void*)(lp), 16, 0, 0)

__device__ __forceinline__ float b2f(short u) {
    union { unsigned int i; float f; } c;
    c.i = ((unsigned int)(unsigned short)u) << 16;
    return c.f;
}
__device__ __forceinline__ unsigned short f2b(float f) {
    __hip_bfloat16 t = __float2bfloat16(f);
    return *(unsigned short*)&t;
}

// ---------------------------------------------------------------------------
// Cast fp32 -> bf16 (RNE), 5 jobs selected by blockIdx.y.
// ---------------------------------------------------------------------------
struct CastArgs {
    const float* src[5];
    unsigned short* dst[5];
    int n[5];
};

__global__ __launch_bounds__(256)
void cast_bf16_kernel(CastArgs a)
{
    const int j = blockIdx.y;
    const float* __restrict__ s = a.src[j];
    unsigned short* __restrict__ d = a.dst[j];
    const int n = a.n[j];
    int i = (blockIdx.x * 256 + threadIdx.x) * 8;
    if (i >= n) return;
    float4 x0 = *(const float4*)&s[i];
    float4 x1 = *(const float4*)&s[i + 4];
    ushort4 o0, o1;
    o0.x = f2b(x0.x); o0.y = f2b(x0.y); o0.z = f2b(x0.z); o0.w = f2b(x0.w);
    o1.x = f2b(x1.x); o1.y = f2b(x1.y); o1.z = f2b(x1.z); o1.w = f2b(x1.w);
    *(ushort4*)&d[i] = o0;
    *(ushort4*)&d[i + 4] = o1;
}

// ---------------------------------------------------------------------------
// MFMA GEMM core: 128x128 tile, BK=64 (16 barriers total), 256 threads
// (4 waves 2x2), bf16 in. LDS 2 x 16 KB.
// ---------------------------------------------------------------------------
__device__ __forceinline__
void gemm_core(const unsigned short* __restrict__ A,
               const unsigned short* __restrict__ W,
               int m0, int n0, unsigned short* As, unsigned short* Bs,
               floatx4 acc[4][4])
{
    const int tid = threadIdx.x;
    const int lane = tid & 63;
    const int wave = tid >> 6;
    const int wm = wave >> 1, wn = wave & 1;
    const int r0 = tid >> 3;            // 0..31
    const int k0 = (tid & 7) * 8;       // 0..56
    const unsigned short* Ag = A + (size_t)(m0 + r0) * 512 + k0;
    const unsigned short* Bg = W + (size_t)(n0 + r0) * 512 + k0;
    const int mrow = lane & 15;
    const int koff = (lane >> 4) * 8;

    for (int kt = 0; kt < 512; kt += 64) {
        __syncthreads();
        GLD16(Ag + kt,            &As[tid * 8]);
        GLD16(Ag + 32 * 512 + kt, &As[2048 + tid * 8]);
        GLD16(Ag + 64 * 512 + kt, &As[4096 + tid * 8]);
        GLD16(Ag + 96 * 512 + kt, &As[6144 + tid * 8]);
        GLD16(Bg + kt,            &Bs[tid * 8]);
        GLD16(Bg + 32 * 512 + kt, &Bs[2048 + tid * 8]);
        GLD16(Bg + 64 * 512 + kt, &Bs[4096 + tid * 8]);
        GLD16(Bg + 96 * 512 + kt, &Bs[6144 + tid * 8]);
        __syncthreads();
        #pragma unroll
        for (int ks = 0; ks < 2; ++ks) {
            short8 af[4], bf[4];
            #pragma unroll
            for (int t = 0; t < 4; ++t) {
                af[t] = *(const short8*)
                    &As[(wm * 64 + t * 16 + mrow) * 64 + ks * 32 + koff];
                bf[t] = *(const short8*)
                    &Bs[(wn * 64 + t * 16 + mrow) * 64 + ks * 32 + koff];
            }
            #pragma unroll
            for (int mt = 0; mt < 4; ++mt)
                #pragma unroll
                for (int nt = 0; nt < 4; ++nt)
                    acc[mt][nt] = __builtin_amdgcn_mfma_f32_16x16x32_bf16(
                        af[mt], bf[nt], acc[mt][nt], 0, 0, 0);
        }
    }
}

// ---------------------------------------------------------------------------
// Fused QKV GEMM. Outputs bf16: q,k as [B,H,N,64]; v transposed [B,H,64,N].
// blockIdx.y in [0,12): y>>2 selects q/k/v, (y&3)*128 = n0.
// ---------------------------------------------------------------------------
__global__ __launch_bounds__(256)
void qkv_gemm_kernel(const unsigned short* __restrict__ A,
                     const unsigned short* __restrict__ W0,
                     const unsigned short* __restrict__ W1,
                     const unsigned short* __restrict__ W2,
                     unsigned short* __restrict__ qo,
                     unsigned short* __restrict__ ko,
                     unsigned short* __restrict__ vto)
{
    __shared__ __align__(16) unsigned short As[128 * 64];
    __shared__ __align__(16) unsigned short Bs[128 * 64];
    const int by = blockIdx.y;
    const int sel = by >> 2;
    const unsigned short* W = (sel == 0) ? W0 : (sel == 1 ? W1 : W2);
    const int m0 = blockIdx.x * 128;
    const int n0 = (by & 3) * 128;

    floatx4 acc[4][4];
    #pragma unroll
    for (int i = 0; i < 4; ++i)
        #pragma unroll
        for (int j = 0; j < 4; ++j)
            acc[i][j] = (floatx4){0.f, 0.f, 0.f, 0.f};

    gemm_core(A, W, m0, n0, As, Bs, acc);

    const int lane = threadIdx.x & 63;
    const int wave = threadIdx.x >> 6;
    const int wm = wave >> 1, wn = wave & 1;
    const int lx = lane & 15;
    const int rq = (lane >> 4) * 4;

    if (sel == 2) {
        // V transposed: [B,H,64,N] — r-direction is token-contiguous.
        #pragma unroll
        for (int mt = 0; mt < 4; ++mt) {
            const int mrow = m0 + wm * 64 + mt * 16 + rq;
            const int bb = mrow >> 10, tok = mrow & 1023;
            #pragma unroll
            for (int nt = 0; nt < 4; ++nt) {
                const int c = n0 + wn * 64 + nt * 16 + lx;
                const int hh = c >> 6, d = c & 63;
                ushort4 pk;
                pk.x = f2b(acc[mt][nt][0]); pk.y = f2b(acc[mt][nt][1]);
                pk.z = f2b(acc[mt][nt][2]); pk.w = f2b(acc[mt][nt][3]);
                *(ushort4*)&vto[((size_t)(bb * H_ + hh) * DK_ + d) * N_ + tok] = pk;
            }
        }
    } else {
        unsigned short* O = (sel == 0) ? qo : ko;
        #pragma unroll
        for (int mt = 0; mt < 4; ++mt) {
            const int mrow = m0 + wm * 64 + mt * 16 + rq;
            const int bb = mrow >> 10, tok = mrow & 1023;
            #pragma unroll
            for (int nt = 0; nt < 4; ++nt) {
                const int c = n0 + wn * 64 + nt * 16 + lx;
                const int hh = c >> 6, d = c & 63;
                unsigned short* p =
                    O + ((size_t)(bb * H_ + hh) * N_ + tok) * DK_ + d;
                #pragma unroll
                for (int r = 0; r < 4; ++r)
                    p[(size_t)r * DK_] = f2b(acc[mt][nt][r]);
            }
        }
    }
}

// ---------------------------------------------------------------------------
// Star-sparse MFMA attention (unchanged from round 3).
// ---------------------------------------------------------------------------
__global__ __launch_bounds__(256)
void attn_kernel(const unsigned short* __restrict__ qg,
                 const unsigned short* __restrict__ kg,
                 const unsigned short* __restrict__ vtg,
                 const float* __restrict__ rpe,
                 unsigned short* __restrict__ ctx)
{
    __shared__ __align__(16) unsigned short P[64 * 136];   // 17.4 KB

    const int tid  = threadIdx.x;
    const int lane = tid & 63;
    const int w    = tid >> 6;
    const int lx   = lane & 15;
    const int quad = lane >> 4;
    const int qb = blockIdx.x * 64;
    const int h  = blockIdx.y, b = blockIdx.z;
    const int bh = b * H_ + h;
    const unsigned short* qh  = qg  + (size_t)bh * N_ * DK_;
    const unsigned short* kh  = kg  + (size_t)bh * N_ * DK_;
    const unsigned short* vth = vtg + (size_t)bh * DK_ * N_;
    const float* rp = rpe + ((size_t)bh * N_ + qb) * N_;
    const bool has_self = (qb >= ST);

    float sself = -1e30f;
    if (has_self) {
        const int i = qb + w * 16 + lx;
        const unsigned short* qr = qh + (size_t)i * DK_ + quad * 16;
        const unsigned short* kr = kh + (size_t)i * DK_ + quad * 16;
        short8 q0 = *(const short8*)qr, q1 = *(const short8*)(qr + 8);
        short8 k0 = *(const short8*)kr, k1 = *(const short8*)(kr + 8);
        float dot = 0.f;
        #pragma unroll
        for (int j = 0; j < 8; ++j) {
            dot = fmaf(b2f(q0[j]), b2f(k0[j]), dot);
            dot = fmaf(b2f(q1[j]), b2f(k1[j]), dot);
        }
        dot += __shfl_xor(dot, 16, 64);
        dot += __shfl_xor(dot, 32, 64);
        const float rd = rp[(size_t)(w * 16 + lx) * N_ + (qb + w * 16 + lx)];
        sself = (dot + rd) * 0.125f;
    }

    float rv[4][8];
    {
        const float* rbase = rp + (size_t)(w * 16 + quad * 4) * N_ + lx;
        #pragma unroll
        for (int r = 0; r < 4; ++r)
            #pragma unroll
            for (int nt = 0; nt < 8; ++nt)
                rv[r][nt] = rbase[(size_t)r * N_ + nt * 16];
    }

    short8 aq[2];
    {
        const unsigned short* qrow =
            qh + (size_t)(qb + w * 16 + lx) * DK_ + quad * 8;
        aq[0] = *(const short8*)qrow;
        aq[1] = *(const short8*)(qrow + 32);
    }
    floatx4 sacc[8];
    #pragma unroll
    for (int nt = 0; nt < 8; ++nt) sacc[nt] = (floatx4){0.f, 0.f, 0.f, 0.f};
    #pragma unroll
    for (int nt = 0; nt < 8; ++nt) {
        const unsigned short* krow =
            kh + (size_t)(nt * 16 + lx) * DK_ + quad * 8;
        short8 b0 = *(const short8*)krow;
        short8 b1 = *(const short8*)(krow + 32);
        sacc[nt] = __builtin_amdgcn_mfma_f32_16x16x32_bf16(aq[0], b0, sacc[nt], 0, 0, 0);
        sacc[nt] = __builtin_amdgcn_mfma_f32_16x16x32_bf16(aq[1], b1, sacc[nt], 0, 0, 0);
    }

    float l4[4], ps4[4];
    #pragma unroll
    for (int r = 0; r < 4; ++r) {
        float sv[8];
        float mx = -1e30f;
        #pragma unroll
        for (int nt = 0; nt < 8; ++nt) {
            sv[nt] = (sacc[nt][r] + rv[r][nt]) * 0.125f;
            mx = fmaxf(mx, sv[nt]);
        }
        #pragma unroll
        for (int o = 1; o < 16; o <<= 1)
            mx = fmaxf(mx, __shfl_xor(mx, o, 64));
        const float ss = __shfl(sself, quad * 4 + r, 64);
        mx = fmaxf(mx, ss);
        float sum = 0.f;
        #pragma unroll
        for (int nt = 0; nt < 8; ++nt) {
            sv[nt] = __expf(sv[nt] - mx);
            sum += sv[nt];
        }
        #pragma unroll
        for (int o = 1; o < 16; o <<= 1)
            sum += __shfl_xor(sum, o, 64);
        const float ps = has_self ? __expf(ss - mx) : 0.f;
        l4[r] = sum + ps;
        ps4[r] = ps;
        const int row = w * 16 + quad * 4 + r;
        #pragma unroll
        for (int nt = 0; nt < 8; ++nt)
            P[row * 136 + nt * 16 + lx] = f2b(sv[nt]);
    }
    __syncthreads();

    short8 ap[4];
    #pragma unroll
    for (int ks = 0; ks < 4; ++ks)
        ap[ks] = *(const short8*)&P[(w * 16 + lx) * 136 + ks * 32 + quad * 8];
    floatx4 oacc[4];
    #pragma unroll
    for (int nt = 0; nt < 4; ++nt) oacc[nt] = (floatx4){0.f, 0.f, 0.f, 0.f};
    #pragma unroll
    for (int nt = 0; nt < 4; ++nt) {
        const unsigned short* vrow = vth + (size_t)(nt * 16 + lx) * N_;
        #pragma unroll
        for (int ks = 0; ks < 4; ++ks) {
            short8 bv = *(const short8*)(vrow + ks * 32 + quad * 8);
            oacc[nt] = __builtin_amdgcn_mfma_f32_16x16x32_bf16(ap[ks], bv, oacc[nt], 0, 0, 0);
        }
    }

    #pragma unroll
    for (int r = 0; r < 4; ++r) {
        const int i = qb + w * 16 + quad * 4 + r;
        const float inv = 1.0f / l4[r];
        const float ps = ps4[r];
        #pragma unroll
        for (int nt = 0; nt < 4; ++nt) {
            const int d = nt * 16 + lx;
            float o = oacc[nt][r];
            if (has_self)
                o = fmaf(ps, b2f((short)vth[(size_t)d * N_ + i]), o);
            ctx[((size_t)(b * N_) + i) * DM + h * DK_ + d] = f2b(o * inv);
        }
    }
}

// ---------------------------------------------------------------------------
// Fused FC + bias + residual + LayerNorm.
// Block = 32 rows x all 512 cols, 256 threads (4 waves; wave w = cols
// [w*128, w*128+128)). A (ctx) staged via GLD16; W streamed from L2.
// Row stats: in-register over ct, shfl over 16 cols, LDS combine over waves.
// ---------------------------------------------------------------------------
__global__ __launch_bounds__(256)
void fc_ln_kernel(const unsigned short* __restrict__ A,
                  const unsigned short* __restrict__ W,
                  const float* __restrict__ bias,
                  const float* __restrict__ resid,
                  const float* __restrict__ g,
                  const float* __restrict__ bb,
                  float* __restrict__ out)
{
    __shared__ __align__(16) unsigned short As[32 * 64];   // 4 KB
    __shared__ float Ssum[32][4], Ssq[32][4];
    __shared__ float Smean[32], Srstd[32];

    const int tid  = threadIdx.x;
    const int lane = tid & 63;
    const int w    = tid >> 6;
    const int lx   = lane & 15;
    const int quad = lane >> 4;
    const int m0 = blockIdx.x * 32;

    const int r0 = tid >> 3;
    const int k0 = (tid & 7) * 8;
    const unsigned short* Ag = A + (size_t)(m0 + r0) * 512 + k0;
    const int koff = quad * 8;

    floatx4 acc[2][8];
    #pragma unroll
    for (int mt = 0; mt < 2; ++mt)
        #pragma unroll
        for (int ct = 0; ct < 8; ++ct)
            acc[mt][ct] = (floatx4){0.f, 0.f, 0.f, 0.f};

    for (int kt = 0; kt < 512; kt += 64) {
        __syncthreads();
        GLD16(Ag + kt, &As[tid * 8]);
        __syncthreads();
        #pragma unroll
        for (int ks = 0; ks < 2; ++ks) {
            short8 af0 = *(const short8*)&As[(lx) * 64 + ks * 32 + koff];
            short8 af1 = *(const short8*)&As[(16 + lx) * 64 + ks * 32 + koff];
            #pragma unroll
            for (int ct = 0; ct < 8; ++ct) {
                const int col = w * 128 + ct * 16 + lx;
                short8 bv = *(const short8*)
                    &W[(size_t)col * 512 + kt + ks * 32 + koff];
                acc[0][ct] = __builtin_amdgcn_mfma_f32_16x16x32_bf16(
                    af0, bv, acc[0][ct], 0, 0, 0);
                acc[1][ct] = __builtin_amdgcn_mfma_f32_16x16x32_bf16(
                    af1, bv, acc[1][ct], 0, 0, 0);
            }
        }
    }

    // bias + resid, row partial stats
    float bias_c[8];
    #pragma unroll
    for (int ct = 0; ct < 8; ++ct)
        bias_c[ct] = bias[w * 128 + ct * 16 + lx];

    float sum[2][4], sq[2][4];
    #pragma unroll
    for (int mt = 0; mt < 2; ++mt)
        #pragma unroll
        for (int r = 0; r < 4; ++r) {
            const int row = m0 + mt * 16 + quad * 4 + r;
            float s = 0.f, q2 = 0.f;
            #pragma unroll
            for (int ct = 0; ct < 8; ++ct) {
                float vvv = acc[mt][ct][r] + bias_c[ct]
                    + resid[(size_t)row * 512 + w * 128 + ct * 16 + lx];
                acc[mt][ct][r] = vvv;
                s += vvv;
                q2 = fmaf(vvv, vvv, q2);
            }
            #pragma unroll
            for (int o = 1; o < 16; o <<= 1) {
                s  += __shfl_xor(s,  o, 64);
                q2 += __shfl_xor(q2, o, 64);
            }
            sum[mt][r] = s; sq[mt][r] = q2;
        }
    if (lx == 0) {
        #pragma unroll
        for (int mt = 0; mt < 2; ++mt)
            #pragma unroll
            for (int r = 0; r < 4; ++r) {
                Ssum[mt * 16 + quad * 4 + r][w] = sum[mt][r];
                Ssq [mt * 16 + quad * 4 + r][w] = sq[mt][r];
            }
    }
    __syncthreads();
    if (tid < 32) {
        float s  = Ssum[tid][0] + Ssum[tid][1] + Ssum[tid][2] + Ssum[tid][3];
        float q2 = Ssq[tid][0]  + Ssq[tid][1]  + Ssq[tid][2]  + Ssq[tid][3];
        const float mean = s * (1.0f / DM);
        const float var  = q2 * (1.0f / DM) - mean * mean;
        Smean[tid] = mean;
        Srstd[tid] = rsqrtf(var + 1e-6f);
    }
    __syncthreads();

    float gv[8], bv2[8];
    #pragma unroll
    for (int ct = 0; ct < 8; ++ct) {
        const int col = w * 128 + ct * 16 + lx;
        gv[ct] = g[col]; bv2[ct] = bb[col];
    }
    #pragma unroll
    for (int mt = 0; mt < 2; ++mt)
        #pragma unroll
        for (int r = 0; r < 4; ++r) {
            const int lrow = mt * 16 + quad * 4 + r;
            const int row  = m0 + lrow;
            const float mean = Smean[lrow], rstd = Srstd[lrow];
            #pragma unroll
            for (int ct = 0; ct < 8; ++ct)
                out[(size_t)row * 512 + w * 128 + ct * 16 + lx] =
                    (acc[mt][ct][r] - mean) * rstd * gv[ct] + bv2[ct];
        }
}

// ---------------------------------------------------------------------------
extern "C" void kernel_launch(void* const* d_in, const int* in_sizes, int n_in,
                              void* d_out, int out_size, void* d_ws, size_t ws_size,
                              hipStream_t stream)
{
    (void)in_sizes; (void)n_in; (void)out_size; (void)ws_size;
    const float* hidden = (const float*)d_in[0];
    const float* rpe    = (const float*)d_in[1];
    const float* Wq     = (const float*)d_in[2];
    const float* Wk     = (const float*)d_in[3];
    const float* Wv     = (const float*)d_in[4];
    const float* fc_w   = (const float*)d_in[5];
    const float* fc_b   = (const float*)d_in[6];
    const float* ln_g   = (const float*)d_in[7];
    const float* ln_b   = (const float*)d_in[8];
    float* out = (float*)d_out;
    char* ws = (char*)d_ws;

    const size_t MB = 1024 * 1024;
    unsigned short* hb  = (unsigned short*)(ws + 0 * MB);    // 8 MB
    unsigned short* wq  = (unsigned short*)(ws + 8 * MB);
    unsigned short* wk  = (unsigned short*)(ws + 8 * MB + 512 * 1024);
    unsigned short* wv  = (unsigned short*)(ws + 9 * MB);
    unsigned short* wf  = (unsigned short*)(ws + 9 * MB + 512 * 1024);
    unsigned short* qB  = (unsigned short*)(ws + 16 * MB);   // [B,H,N,64]
    unsigned short* kB  = (unsigned short*)(ws + 24 * MB);   // [B,H,N,64]
    unsigned short* vtB = (unsigned short*)(ws + 32 * MB);   // [B,H,64,N]
    unsigned short* cb  = (unsigned short*)(ws + 40 * MB);   // ctx bf16

    CastArgs ca;
    ca.src[0] = hidden; ca.dst[0] = hb; ca.n[0] = B_ * N_ * DM;
    ca.src[1] = Wq;     ca.dst[1] = wq; ca.n[1] = DM * DM;
    ca.src[2] = Wk;     ca.dst[2] = wk; ca.n[2] = DM * DM;
    ca.src[3] = Wv;     ca.dst[3] = wv; ca.n[3] = DM * DM;
    ca.src[4] = fc_w;   ca.dst[4] = wf; ca.n[4] = DM * DM;
    cast_bf16_kernel<<<dim3(2048, 5), 256, 0, stream>>>(ca);

    qkv_gemm_kernel<<<dim3(64, 12), 256, 0, stream>>>(hb, wq, wk, wv, qB, kB, vtB);
    attn_kernel<<<dim3(16, H_, B_), 256, 0, stream>>>(qB, kB, vtB, rpe, cb);
    fc_ln_kernel<<<256, 256, 0, stream>>>(cb, wf, fc_b, hidden, ln_g, ln_b, out);
}